// Round 6
// baseline (988.950 us; speedup 1.0000x reference)
//
#include <hip/hip_runtime.h>

#define H 181
#define T_LEN 1024
#define BB 16            // batch rows per block
#define NBLK 64          // 64 * 16 = 1024
#define NTHR 768         // 12 waves, 3 per SIMD
#define KT 6             // K tiles of 32 -> 192 >= 181
#define FRAG 512         // shorts per kt fragment (64 lanes x 8)
#define JP 192           // padded hidden dim
#define XST 1058         // x_s row stride (even -> 8B-aligned b64 reads; 2-way banks free)

typedef __attribute__((ext_vector_type(8))) short short8;
typedef __attribute__((ext_vector_type(4))) float floatx4;
typedef __attribute__((ext_vector_type(2))) float floatx2;

#define LOG2E 1.4426950408889634f

__device__ __forceinline__ float rcpf(float x) { return __builtin_amdgcn_rcpf(x); }
__device__ __forceinline__ float exp2f_hw(float x) { return __builtin_amdgcn_exp2f(x); }

__device__ __forceinline__ unsigned f2bf_u(float f) {
    unsigned u = __float_as_uint(f);
    return (u + 0x7fff + ((u >> 16) & 1)) >> 16;   // RNE (used init-path only)
}
// pack two fp32 -> bf16x2 with round-half-up: 2 adds + 1 v_perm
__device__ __forceinline__ unsigned pack_bf16_rh(float f0, float f1) {
    unsigned u0 = __float_as_uint(f0) + 0x8000u;
    unsigned u1 = __float_as_uint(f1) + 0x8000u;
    return __builtin_amdgcn_perm(u1, u0, 0x07060302u);  // [u1.hi16 | u0.hi16]
}

// 64 persistent blocks x 16 batch, 12 waves (3/SIMD).
// A = scaled w_hh (registers, m = unit), B = h (LDS, n = batch), h stored in
// exact MFMA B-fragment order (conflict-free lane*16 reads; packed b64 write
// back into the frag slot). log2e folded into weights; biases pre-seeded in
// accumulators; gates via raw v_exp/v_rcp; gate arithmetic on float2 vectors
// to select full-rate v_pk_* ops. Pad units (181..191) carry garbage h; their
// A-weights are zero so MFMA ignores them.
__launch_bounds__(NTHR, 3)
__global__ void gru_mfma(const float* __restrict__ x,
                         const float* __restrict__ w_ih,
                         const float* __restrict__ w_hh,
                         const float* __restrict__ b_ih,
                         const float* __restrict__ b_hh,
                         const float* __restrict__ w_fc,
                         const float* __restrict__ b_fc,
                         float* __restrict__ out) {
    __shared__ __align__(16) unsigned short hfr_s[2 * KT * FRAG];  // 24 KB dbuf
    __shared__ __align__(16) float x_s[16 * XST];                  // x [bb][t]; reused for FC

    const int tid  = threadIdx.x;
    const int wv   = tid >> 6;          // unit tile jt = wv (0..11)
    const int lane = tid & 63;
    const int col  = lane & 15;         // batch index
    const int q    = lane >> 4;
    const int b0   = blockIdx.x * BB;
    const int jt   = wv;

    // ---- A fragments: scaled w_hh in registers, [gate][kt] ----
    const int  mu = jt * 16 + col;
    const bool mv = (mu < H);
    const float gscale[3] = {-LOG2E, -LOG2E, 2.0f * LOG2E};
    short8 afr[3][KT];
    #pragma unroll
    for (int g = 0; g < 3; ++g) {
        const float* wrow = w_hh + (size_t)(g * H + (mv ? mu : 0)) * H;
        #pragma unroll
        for (int kt = 0; kt < KT; ++kt) {
            short8 f;
            #pragma unroll
            for (int e = 0; e < 8; ++e) {
                int k = kt * 32 + q * 8 + e;
                float v = (mv && k < H) ? gscale[g] * wrow[k] : 0.0f;
                f[e] = (short)f2bf_u(v);
            }
            afr[g][kt] = f;
        }
    }

    // ---- per-lane unit params (units j0..j0+3) as float2 pairs, log2e folded ----
    const int j0 = jt * 16 + q * 4;
    floatx2 wrS[2], wzS[2], wnS[2], bnI[2];
    floatx4 seedR, seedZ, seedN;
    #pragma unroll
    for (int r = 0; r < 4; ++r) {
        int j = j0 + r;
        bool v = (j < H);
        wrS[r >> 1][r & 1] = v ? -LOG2E * w_ih[j]              : 0.0f;
        wzS[r >> 1][r & 1] = v ? -LOG2E * w_ih[H + j]          : 0.0f;
        wnS[r >> 1][r & 1] = v ?  2.0f * LOG2E * w_ih[2*H + j] : 0.0f;
        bnI[r >> 1][r & 1] = v ?  2.0f * LOG2E * b_ih[2*H + j] : 0.0f;
        seedR[r] = v ? -LOG2E * (b_ih[j] + b_hh[j])         : 0.0f;
        seedZ[r] = v ? -LOG2E * (b_ih[H+j] + b_hh[H+j])     : 0.0f;
        seedN[r] = v ?  2.0f * LOG2E * b_hh[2*H + j]        : 0.0f;
    }

    // ---- frag-slot address for this lane's h write ----
    const int wkt  = j0 >> 5;
    const int wq   = (j0 >> 3) & 3;
    const int we   = j0 & 7;
    const int woff = wkt * FRAG + (wq * 16 + col) * 8 + we;
    const int rbase = lane * 8;

    // ---- stage x coalesced into [bb][t] ----
    for (int i = tid; i < BB * T_LEN; i += NTHR) {
        int bb = i >> 10, t = i & 1023;
        x_s[bb * XST + t] = x[(size_t)b0 * T_LEN + i];
    }
    for (int i = tid; i < 2 * KT * FRAG; i += NTHR) hfr_s[i] = 0;
    __syncthreads();

    floatx2 h2[2] = {{0.f, 0.f}, {0.f, 0.f}};   // units j0+{0,1},{2,3}, batch col

    auto step = [&](const unsigned short* rb, unsigned short* wb, float xv) {
        short8 bfrg[KT];
        #pragma unroll
        for (int kt = 0; kt < KT; ++kt)
            bfrg[kt] = *(const short8*)&rb[kt * FRAG + rbase];

        floatx4 aR = seedR, aZ = seedZ, aN = seedN;
        #pragma unroll
        for (int kt = 0; kt < KT; ++kt) {
            aR = __builtin_amdgcn_mfma_f32_16x16x32_bf16(afr[0][kt], bfrg[kt], aR, 0, 0, 0);
            aZ = __builtin_amdgcn_mfma_f32_16x16x32_bf16(afr[1][kt], bfrg[kt], aZ, 0, 0, 0);
            aN = __builtin_amdgcn_mfma_f32_16x16x32_bf16(afr[2][kt], bfrg[kt], aN, 0, 0, 0);
        }

        const floatx2 xv2 = {xv, xv};
        floatx2 er[2], ez[2], rr2[2], zz2[2], en[2];
        #pragma unroll
        for (int p = 0; p < 2; ++p) {
            floatx2 aR2 = {aR[2*p], aR[2*p+1]};
            floatx2 gr  = __builtin_elementwise_fma(xv2, wrS[p], aR2);
            er[p][0] = exp2f_hw(gr[0]); er[p][1] = exp2f_hw(gr[1]);
        }
        #pragma unroll
        for (int p = 0; p < 2; ++p) {
            floatx2 aZ2 = {aZ[2*p], aZ[2*p+1]};
            floatx2 gz  = __builtin_elementwise_fma(xv2, wzS[p], aZ2);
            ez[p][0] = exp2f_hw(gz[0]); ez[p][1] = exp2f_hw(gz[1]);
        }
        #pragma unroll
        for (int p = 0; p < 2; ++p) {
            floatx2 d1 = er[p] + 1.0f;
            floatx2 d2 = ez[p] + 1.0f;
            rr2[p][0] = rcpf(d1[0]); rr2[p][1] = rcpf(d1[1]);
            zz2[p][0] = rcpf(d2[0]); zz2[p][1] = rcpf(d2[1]);
        }
        #pragma unroll
        for (int p = 0; p < 2; ++p) {
            floatx2 aN2 = {aN[2*p], aN[2*p+1]};
            floatx2 gi  = __builtin_elementwise_fma(xv2, wnS[p], bnI[p]);
            floatx2 gn  = __builtin_elementwise_fma(rr2[p], aN2, gi);
            en[p][0] = exp2f_hw(gn[0]); en[p][1] = exp2f_hw(gn[1]);
        }
        unsigned pk[2];
        #pragma unroll
        for (int p = 0; p < 2; ++p) {
            floatx2 dn = en[p] + 1.0f;
            floatx2 rn = {rcpf(dn[0]), rcpf(dn[1])};
            floatx2 nn = __builtin_elementwise_fma((floatx2){-2.f, -2.f}, rn,
                                                   (floatx2){1.f, 1.f});
            floatx2 dh = h2[p] - nn;
            h2[p] = __builtin_elementwise_fma(zz2[p], dh, nn);
            pk[p] = pack_bf16_rh(h2[p][0], h2[p][1]);
        }
        *(uint2*)&wb[woff] = make_uint2(pk[0], pk[1]);
        __syncthreads();
    };

    const float* xrow = &x_s[col * XST];
    for (int t = 0; t < T_LEN; t += 2) {
        floatx2 xv2 = *(const floatx2*)&xrow[t];     // one b64, covers both steps
        step(hfr_s,             hfr_s + KT * FRAG, xv2[0]);
        step(hfr_s + KT * FRAG, hfr_s,             xv2[1]);
    }

    // ---- final FC; reuse x_s as fp32 h buffer ----
    float* hfin = x_s;
    floatx4 hv = {h2[0][0], h2[0][1], h2[1][0], h2[1][1]};
    *(floatx4*)&hfin[col * JP + j0] = hv;
    __syncthreads();
    if (tid < BB * 10) {
        int bb = tid / 10, c = tid % 10;
        float acc = b_fc[c];
        for (int k = 0; k < H; ++k)
            acc = fmaf(hfin[bb * JP + k], w_fc[c * H + k], acc);
        out[(b0 + bb) * 10 + c] = acc;
    }
}

extern "C" void kernel_launch(void* const* d_in, const int* in_sizes, int n_in,
                              void* d_out, int out_size, void* d_ws, size_t ws_size,
                              hipStream_t stream) {
    const float* x    = (const float*)d_in[0];
    const float* w_ih = (const float*)d_in[1];
    const float* w_hh = (const float*)d_in[2];
    const float* b_ih = (const float*)d_in[3];
    const float* b_hh = (const float*)d_in[4];
    const float* w_fc = (const float*)d_in[5];
    const float* b_fc = (const float*)d_in[6];
    float* out = (float*)d_out;

    gru_mfma<<<NBLK, NTHR, 0, stream>>>(x, w_ih, w_hh, b_ih, b_hh, w_fc, b_fc, out);
}

// Round 7
// 944.235 us; speedup vs baseline: 1.0474x; 1.0474x over previous
//
#include <hip/hip_runtime.h>
#include <hip/hip_fp16.h>

#define H 181
#define T_LEN 1024
#define BB 16            // batch rows per block
#define NBLK 64          // 64 * 16 = 1024
#define NTHR 768         // 12 waves, 3 per SIMD
#define KT 6             // K tiles of 32 -> 192 >= 181
#define FRAG 512         // shorts per kt fragment (64 lanes x 8)
#define JP 192           // padded hidden dim
#define XST 1058         // x_s row stride (even -> 8B-aligned b64 reads)

typedef _Float16 half8 __attribute__((ext_vector_type(8)));
typedef __attribute__((ext_vector_type(4))) float floatx4;
typedef __attribute__((ext_vector_type(2))) float floatx2;

#define LOG2E 1.4426950408889634f

// 64 persistent blocks x 16 batch, 12 waves (3/SIMD).
// FP16 datapath: A = scaled w_hh (f16, registers, m = unit), B = h (f16, LDS,
// n = batch) in exact MFMA B-fragment order (conflict-free lane*16 reads; one
// packed b64 write back into the frag slot). log2e folded into weights; biases
// pre-seeded in fp32 accumulators; gate phase entirely in packed f16
// (v_pk_fma_f16 / v_exp_f16 / v_rcp_f16). Pre-activations saturate safely in
// f16: exp2(+big)=inf -> rcp -> 0; exp2(-big)=0 -> rcp(1) = 1.
// Pad units (181..191) carry garbage h; their A-weights are zero.
__launch_bounds__(NTHR, 3)
__global__ void gru_mfma(const float* __restrict__ x,
                         const float* __restrict__ w_ih,
                         const float* __restrict__ w_hh,
                         const float* __restrict__ b_ih,
                         const float* __restrict__ b_hh,
                         const float* __restrict__ w_fc,
                         const float* __restrict__ b_fc,
                         float* __restrict__ out) {
    __shared__ __align__(16) unsigned short hfr_s[2 * KT * FRAG];  // 24 KB dbuf (f16)
    __shared__ __align__(16) float x_s[16 * XST];                  // x [bb][t]; reused for FC

    const int tid  = threadIdx.x;
    const int wv   = tid >> 6;          // unit tile jt = wv (0..11)
    const int lane = tid & 63;
    const int col  = lane & 15;         // batch index
    const int q    = lane >> 4;
    const int b0   = blockIdx.x * BB;
    const int jt   = wv;

    // ---- A fragments: scaled w_hh in f16 registers, [gate][kt] ----
    const int  mu = jt * 16 + col;
    const bool mv = (mu < H);
    const float gscale[3] = {-LOG2E, -LOG2E, 2.0f * LOG2E};
    half8 afr[3][KT];
    #pragma unroll
    for (int g = 0; g < 3; ++g) {
        const float* wrow = w_hh + (size_t)(g * H + (mv ? mu : 0)) * H;
        #pragma unroll
        for (int kt = 0; kt < KT; ++kt) {
            half8 f;
            #pragma unroll
            for (int e = 0; e < 8; ++e) {
                int k = kt * 32 + q * 8 + e;
                float v = (mv && k < H) ? gscale[g] * wrow[k] : 0.0f;
                f[e] = (_Float16)v;
            }
            afr[g][kt] = f;
        }
    }

    // ---- per-lane unit params: f16 half2 pairs (units j0+2p, j0+2p+1) ----
    const int j0 = jt * 16 + q * 4;
    __half2 wrS2[2], wzS2[2], wnS2[2], bnI2[2];
    floatx4 seedR, seedZ, seedN;            // fp32 acc seeds (fused biases)
    #pragma unroll
    for (int p = 0; p < 2; ++p) {
        float v0[4], v1[4];
        #pragma unroll
        for (int s = 0; s < 2; ++s) {
            int j = j0 + 2 * p + s;
            bool v = (j < H);
            float* dst = s ? v1 : v0;
            dst[0] = v ? -LOG2E * w_ih[j]              : 0.0f;
            dst[1] = v ? -LOG2E * w_ih[H + j]          : 0.0f;
            dst[2] = v ?  2.0f * LOG2E * w_ih[2*H + j] : 0.0f;
            dst[3] = v ?  2.0f * LOG2E * b_ih[2*H + j] : 0.0f;
        }
        wrS2[p] = __floats2half2_rn(v0[0], v1[0]);
        wzS2[p] = __floats2half2_rn(v0[1], v1[1]);
        wnS2[p] = __floats2half2_rn(v0[2], v1[2]);
        bnI2[p] = __floats2half2_rn(v0[3], v1[3]);
    }
    #pragma unroll
    for (int r = 0; r < 4; ++r) {
        int j = j0 + r;
        bool v = (j < H);
        seedR[r] = v ? -LOG2E * (b_ih[j] + b_hh[j])     : 0.0f;
        seedZ[r] = v ? -LOG2E * (b_ih[H+j] + b_hh[H+j]) : 0.0f;
        seedN[r] = v ?  2.0f * LOG2E * b_hh[2*H + j]    : 0.0f;
    }

    // ---- frag-slot address for this lane's h write ----
    const int wkt  = j0 >> 5;
    const int wq   = (j0 >> 3) & 3;
    const int we   = j0 & 7;
    const int woff = wkt * FRAG + (wq * 16 + col) * 8 + we;
    const int rbase = lane * 8;

    // ---- stage x coalesced into [bb][t] ----
    for (int i = tid; i < BB * T_LEN; i += NTHR) {
        int bb = i >> 10, t = i & 1023;
        x_s[bb * XST + t] = x[(size_t)b0 * T_LEN + i];
    }
    for (int i = tid; i < 2 * KT * FRAG; i += NTHR) hfr_s[i] = 0;
    __syncthreads();

    const __half2 one2 = __float2half2_rn(1.0f);
    const __half2 m2   = __float2half2_rn(-2.0f);
    __half2 h2[2] = {__float2half2_rn(0.0f), __float2half2_rn(0.0f)};

    auto step = [&](const unsigned short* rb, unsigned short* wb, float xv) {
        half8 bfrg[KT];
        #pragma unroll
        for (int kt = 0; kt < KT; ++kt)
            bfrg[kt] = *(const half8*)&rb[kt * FRAG + rbase];

        floatx4 aR = seedR, aZ = seedZ, aN = seedN;
        #pragma unroll
        for (int kt = 0; kt < KT; ++kt) {
            aR = __builtin_amdgcn_mfma_f32_16x16x32_f16(afr[0][kt], bfrg[kt], aR, 0, 0, 0);
            aZ = __builtin_amdgcn_mfma_f32_16x16x32_f16(afr[1][kt], bfrg[kt], aZ, 0, 0, 0);
            aN = __builtin_amdgcn_mfma_f32_16x16x32_f16(afr[2][kt], bfrg[kt], aN, 0, 0, 0);
        }

        const __half2 xv2 = __float2half2_rn(xv);
        unsigned pk[2];
        #pragma unroll
        for (int p = 0; p < 2; ++p) {
            __half2 aR2 = __builtin_bit_cast(__half2,
                __builtin_amdgcn_cvt_pkrtz(aR[2*p], aR[2*p+1]));
            __half2 aZ2 = __builtin_bit_cast(__half2,
                __builtin_amdgcn_cvt_pkrtz(aZ[2*p], aZ[2*p+1]));
            __half2 aN2 = __builtin_bit_cast(__half2,
                __builtin_amdgcn_cvt_pkrtz(aN[2*p], aN[2*p+1]));

            __half2 gr = __hfma2(xv2, wrS2[p], aR2);
            __half2 gz = __hfma2(xv2, wzS2[p], aZ2);
            __half2 er = h2exp2(gr);
            __half2 ez = h2exp2(gz);
            __half2 rr = h2rcp(__hadd2(er, one2));
            __half2 zz = h2rcp(__hadd2(ez, one2));
            __half2 gi = __hfma2(xv2, wnS2[p], bnI2[p]);
            __half2 gn = __hfma2(rr, aN2, gi);
            __half2 en = h2exp2(gn);
            __half2 rn = h2rcp(__hadd2(en, one2));
            __half2 nn = __hfma2(m2, rn, one2);          // tanh
            __half2 dh = __hsub2(h2[p], nn);
            h2[p] = __hfma2(zz, dh, nn);                 // n + z*(h-n)
            pk[p] = __builtin_bit_cast(unsigned, h2[p]);
        }
        *(uint2*)&wb[woff] = make_uint2(pk[0], pk[1]);
        __syncthreads();
    };

    const float* xrow = &x_s[col * XST];
    for (int t = 0; t < T_LEN; t += 2) {
        floatx2 xv2 = *(const floatx2*)&xrow[t];
        step(hfr_s,             hfr_s + KT * FRAG, xv2[0]);
        step(hfr_s + KT * FRAG, hfr_s,             xv2[1]);
    }

    // ---- final FC; reuse x_s as fp32 h buffer ----
    float* hfin = x_s;
    floatx4 hv = {__half2float(__low2half(h2[0])),  __half2float(__high2half(h2[0])),
                  __half2float(__low2half(h2[1])),  __half2float(__high2half(h2[1]))};
    *(floatx4*)&hfin[col * JP + j0] = hv;
    __syncthreads();
    if (tid < BB * 10) {
        int bb = tid / 10, c = tid % 10;
        float acc = b_fc[c];
        for (int k = 0; k < H; ++k)
            acc = fmaf(hfin[bb * JP + k], w_fc[c * H + k], acc);
        out[(b0 + bb) * 10 + c] = acc;
    }
}

extern "C" void kernel_launch(void* const* d_in, const int* in_sizes, int n_in,
                              void* d_out, int out_size, void* d_ws, size_t ws_size,
                              hipStream_t stream) {
    const float* x    = (const float*)d_in[0];
    const float* w_ih = (const float*)d_in[1];
    const float* w_hh = (const float*)d_in[2];
    const float* b_ih = (const float*)d_in[3];
    const float* b_hh = (const float*)d_in[4];
    const float* w_fc = (const float*)d_in[5];
    const float* b_fc = (const float*)d_in[6];
    float* out = (float*)d_out;

    gru_mfma<<<NBLK, NTHR, 0, stream>>>(x, w_ih, w_hh, b_ih, b_hh, w_fc, b_fc, out);
}

// Round 8
// 931.274 us; speedup vs baseline: 1.0619x; 1.0139x over previous
//
#include <hip/hip_runtime.h>
#include <hip/hip_fp16.h>

#define H 181
#define T_LEN 1024
#define BB 16            // batch rows per block
#define NBLK 64          // 64 * 16 = 1024
#define NTHR 768         // 12 waves, 3 per SIMD
#define KT 6             // K tiles of 32 -> 192 >= 181
#define FRAG 512         // shorts per kt fragment (64 lanes x 8)
#define JP 192           // padded hidden dim
#define XST 1058         // x_s row stride

typedef _Float16 half8 __attribute__((ext_vector_type(8)));
typedef _Float16 half2v __attribute__((ext_vector_type(2)));
typedef __attribute__((ext_vector_type(4))) float floatx4;
typedef __attribute__((ext_vector_type(2))) float floatx2;

#define LOG2E 1.4426950408889634f

// Schraudolph exp2 (balanced sawtooth, |rel err| <= ~3%):
//   bits = (g + 127)*2^23 - 0.043*2^23, clamped to g in [-20, +14].
#define SCH_C  1064992506.0f   // (127 - 0.043) * 2^23
#define SCH_LO 897220352.0f    // g = -20  -> e = 2^-20 (sigma -> 1)
#define SCH_HI 1182433024.0f   // g = +14  -> e ~ 2^14  (sigma -> 0; product-safe)

__device__ __forceinline__ float exp2_fast(float g) {
    float s = fmaf(g, 8388608.0f, SCH_C);
    s = fminf(fmaxf(s, SCH_LO), SCH_HI);       // folds to v_med3_f32
    return __uint_as_float((unsigned)s);
}
__device__ __forceinline__ float rcpf(float x) { return __builtin_amdgcn_rcpf(x); }
__device__ __forceinline__ float exp2f_hw(float x) { return __builtin_amdgcn_exp2f(x); }

// 64 persistent blocks x 16 batch, 12 waves (3/SIMD).
// A = scaled w_hh (f16 regs, m = unit), B = h (f16 LDS, n = batch) in exact
// MFMA B-fragment order (conflict-free lane*16 reads; one packed b64 write).
// log2e folded into weights; biases pre-seeded in fp32 accumulators.
// Gate phase f32: r,z sigmoids via Schraudolph exp2 (3 full-rate ops each),
// n tanh via exact v_exp_f32; ALL 12 reciprocals batched into 2 v_rcp_f32
// via prefix-product group inversion. Pad units carry zero A-weights.
__launch_bounds__(NTHR, 3)
__global__ void gru_mfma(const float* __restrict__ x,
                         const float* __restrict__ w_ih,
                         const float* __restrict__ w_hh,
                         const float* __restrict__ b_ih,
                         const float* __restrict__ b_hh,
                         const float* __restrict__ w_fc,
                         const float* __restrict__ b_fc,
                         float* __restrict__ out) {
    __shared__ __align__(16) unsigned short hfr_s[2 * KT * FRAG];  // 24 KB dbuf (f16)
    __shared__ __align__(16) float x_s[16 * XST];                  // x [bb][t]; reused for FC

    const int tid  = threadIdx.x;
    const int wv   = tid >> 6;
    const int lane = tid & 63;
    const int col  = lane & 15;
    const int q    = lane >> 4;
    const int b0   = blockIdx.x * BB;
    const int jt   = wv;

    // ---- A fragments: scaled w_hh in f16 registers, [gate][kt] ----
    const int  mu = jt * 16 + col;
    const bool mv = (mu < H);
    const float gscale[3] = {-LOG2E, -LOG2E, 2.0f * LOG2E};
    half8 afr[3][KT];
    #pragma unroll
    for (int g = 0; g < 3; ++g) {
        const float* wrow = w_hh + (size_t)(g * H + (mv ? mu : 0)) * H;
        #pragma unroll
        for (int kt = 0; kt < KT; ++kt) {
            half8 f;
            #pragma unroll
            for (int e = 0; e < 8; ++e) {
                int k = kt * 32 + q * 8 + e;
                float v = (mv && k < H) ? gscale[g] * wrow[k] : 0.0f;
                f[e] = (_Float16)v;
            }
            afr[g][kt] = f;
        }
    }

    // ---- per-lane unit params (units j0..j0+3), log2e pre-folded, f32 ----
    const int j0 = jt * 16 + q * 4;
    float wrS[4], wzS[4], wnS[4], bnI[4];
    floatx4 seedR, seedZ, seedN;
    #pragma unroll
    for (int r = 0; r < 4; ++r) {
        int j = j0 + r;
        bool v = (j < H);
        wrS[r]  = v ? -LOG2E * w_ih[j]              : 0.0f;
        wzS[r]  = v ? -LOG2E * w_ih[H + j]          : 0.0f;
        wnS[r]  = v ?  2.0f * LOG2E * w_ih[2*H + j] : 0.0f;
        bnI[r]  = v ?  2.0f * LOG2E * b_ih[2*H + j] : 0.0f;
        seedR[r] = v ? -LOG2E * (b_ih[j] + b_hh[j])     : 0.0f;
        seedZ[r] = v ? -LOG2E * (b_ih[H+j] + b_hh[H+j]) : 0.0f;
        seedN[r] = v ?  2.0f * LOG2E * b_hh[2*H + j]    : 0.0f;
    }

    // ---- frag-slot address for this lane's h write ----
    const int wkt  = j0 >> 5;
    const int wq   = (j0 >> 3) & 3;
    const int we   = j0 & 7;
    const int woff = wkt * FRAG + (wq * 16 + col) * 8 + we;
    const int rbase = lane * 8;

    // ---- stage x coalesced into [bb][t] ----
    for (int i = tid; i < BB * T_LEN; i += NTHR) {
        int bb = i >> 10, t = i & 1023;
        x_s[bb * XST + t] = x[(size_t)b0 * T_LEN + i];
    }
    for (int i = tid; i < 2 * KT * FRAG; i += NTHR) hfr_s[i] = 0;
    __syncthreads();

    float h[4] = {0.f, 0.f, 0.f, 0.f};

    auto step = [&](const unsigned short* rb, unsigned short* wb, float xv) {
        half8 bfrg[KT];
        #pragma unroll
        for (int kt = 0; kt < KT; ++kt)
            bfrg[kt] = *(const half8*)&rb[kt * FRAG + rbase];

        floatx4 aR = seedR, aZ = seedZ, aN = seedN;
        #pragma unroll
        for (int kt = 0; kt < KT; ++kt) {
            aR = __builtin_amdgcn_mfma_f32_16x16x32_f16(afr[0][kt], bfrg[kt], aR, 0, 0, 0);
            aZ = __builtin_amdgcn_mfma_f32_16x16x32_f16(afr[1][kt], bfrg[kt], aZ, 0, 0, 0);
            aN = __builtin_amdgcn_mfma_f32_16x16x32_f16(afr[2][kt], bfrg[kt], aN, 0, 0, 0);
        }

        // ---- r,z: Schraudolph exp2, denominators d[0..7] ----
        float d[8];
        #pragma unroll
        for (int r = 0; r < 4; ++r)
            d[r]     = 1.0f + exp2_fast(fmaf(xv, wrS[r], aR[r]));
        #pragma unroll
        for (int r = 0; r < 4; ++r)
            d[4 + r] = 1.0f + exp2_fast(fmaf(xv, wzS[r], aZ[r]));

        // grouped inversion of 8 denominators: 1 v_rcp + 21 mul
        float p[8];
        p[0] = d[0];
        #pragma unroll
        for (int i = 1; i < 8; ++i) p[i] = p[i - 1] * d[i];
        float qv = rcpf(p[7]);
        float inv[8];
        #pragma unroll
        for (int i = 7; i >= 1; --i) {
            inv[i] = qv * p[i - 1];
            qv = qv * d[i];
        }
        inv[0] = qv;

        // ---- n gate: exact exp2, grouped-4 inversion ----
        float dn[4];
        #pragma unroll
        for (int r = 0; r < 4; ++r) {
            float gn = fmaf(inv[r], aN[r], fmaf(xv, wnS[r], bnI[r]));
            dn[r] = 1.0f + exp2f_hw(fminf(gn, 30.0f));
        }
        float pn[4];
        pn[0] = dn[0];
        #pragma unroll
        for (int i = 1; i < 4; ++i) pn[i] = pn[i - 1] * dn[i];
        float qn = rcpf(pn[3]);
        float rn[4];
        #pragma unroll
        for (int i = 3; i >= 1; --i) {
            rn[i] = qn * pn[i - 1];
            qn = qn * dn[i];
        }
        rn[0] = qn;

        #pragma unroll
        for (int r = 0; r < 4; ++r) {
            float nn = fmaf(-2.0f, rn[r], 1.0f);       // tanh
            h[r] = fmaf(inv[4 + r], h[r] - nn, nn);    // n + z*(h-n)
        }
        unsigned pk0 = __builtin_bit_cast(unsigned,
                           __builtin_amdgcn_cvt_pkrtz(h[0], h[1]));
        unsigned pk1 = __builtin_bit_cast(unsigned,
                           __builtin_amdgcn_cvt_pkrtz(h[2], h[3]));
        *(uint2*)&wb[woff] = make_uint2(pk0, pk1);
        __syncthreads();
    };

    const float* xrow = &x_s[col * XST];
    for (int t = 0; t < T_LEN; t += 2) {
        floatx2 xv2 = *(const floatx2*)&xrow[t];
        step(hfr_s,             hfr_s + KT * FRAG, xv2[0]);
        step(hfr_s + KT * FRAG, hfr_s,             xv2[1]);
    }

    // ---- final FC; reuse x_s as fp32 h buffer ----
    float* hfin = x_s;
    floatx4 hv = {h[0], h[1], h[2], h[3]};
    *(floatx4*)&hfin[col * JP + j0] = hv;
    __syncthreads();
    if (tid < BB * 10) {
        int bb = tid / 10, c = tid % 10;
        float acc = b_fc[c];
        for (int k = 0; k < H; ++k)
            acc = fmaf(hfin[bb * JP + k], w_fc[c * H + k], acc);
        out[(b0 + bb) * 10 + c] = acc;
    }
}

extern "C" void kernel_launch(void* const* d_in, const int* in_sizes, int n_in,
                              void* d_out, int out_size, void* d_ws, size_t ws_size,
                              hipStream_t stream) {
    const float* x    = (const float*)d_in[0];
    const float* w_ih = (const float*)d_in[1];
    const float* w_hh = (const float*)d_in[2];
    const float* b_ih = (const float*)d_in[3];
    const float* b_hh = (const float*)d_in[4];
    const float* w_fc = (const float*)d_in[5];
    const float* b_fc = (const float*)d_in[6];
    float* out = (float*)d_out;

    gru_mfma<<<NBLK, NTHR, 0, stream>>>(x, w_ih, w_hh, b_ih, b_hh, w_fc, b_fc, out);
}